// Round 1
// baseline (1284.486 us; speedup 1.0000x reference)
//
#include <hip/hip_runtime.h>
#include <hip/hip_bf16.h>
#include <stdint.h>
#include <stddef.h>

using bf16 = __hip_bfloat16;
typedef __attribute__((ext_vector_type(8))) short short8;   // 8 bf16 (4 VGPRs)
typedef __attribute__((ext_vector_type(4))) float f32x4;

#define T_TOK 2048
#define HD    2048
#define NH    32
#define NKV   16
#define DKh   128
#define DVh   128

// ---------- helpers ----------
__device__ __forceinline__ void bf2f(uint32_t u, float& a, float& b) {
    union { uint32_t i; float f; } x;
    x.i = u << 16;          a = x.f;
    x.i = u & 0xffff0000u;  b = x.f;
}

__device__ __forceinline__ void gload16(const void* g, void* l) {
    __builtin_amdgcn_global_load_lds(
        (const __attribute__((address_space(1))) void*)g,
        (__attribute__((address_space(3))) void*)l, 16, 0, 0);
}

__device__ __forceinline__ void store_c(bf16* C, size_t off, float v) { C[off] = __float2bfloat16(v); }
__device__ __forceinline__ void store_c(float* C, size_t off, float v) { C[off] = v; }

// DPP butterfly add within rows of 16 lanes (VALU latency, no LDS)
template <int CTRL>
__device__ __forceinline__ float dppadd(float x) {
    int y = __builtin_amdgcn_update_dpp(0, __float_as_int(x), CTRL, 0xf, 0xf, true);
    return x + __int_as_float(y);
}
__device__ __forceinline__ float red16(float x) {
    x = dppadd<0xB1>(x);    // quad_perm [1,0,3,2]  : xor 1
    x = dppadd<0x4E>(x);    // quad_perm [2,3,0,1]  : xor 2
    x = dppadd<0x141>(x);   // row_half_mirror      : xor 4
    x = dppadd<0x140>(x);   // row_mirror           : xor 8
    return x;
}
// 32-lane butterfly: 4 DPP stages + xor-16 via ds_swizzle (BitMode, 32-lane groups)
__device__ __forceinline__ float red32(float x) {
    x = dppadd<0xB1>(x);    // xor 1
    x = dppadd<0x4E>(x);    // xor 2
    x = dppadd<0x141>(x);   // xor 4
    x = dppadd<0x140>(x);   // xor 8
    int y = __builtin_amdgcn_ds_swizzle(__float_as_int(x), 0x401F);  // xor 16
    return x + __int_as_float(y);
}

// ---------- convert fp32 -> bf16 elementwise ----------
__global__ __launch_bounds__(256) void f2b_kernel(
    const float* __restrict__ in, bf16* __restrict__ out, int n)
{
    int i = blockIdx.x * 256 + threadIdx.x;
    if (i < n) out[i] = __float2bfloat16(in[i]);
}

// ---------- transpose+convert: in fp32 [R][C] -> out bf16 [C][R] ----------
__global__ __launch_bounds__(256) void transpose_kernel(
    const float* __restrict__ in, bf16* __restrict__ out, int R, int C)
{
    __shared__ bf16 tile[32][33];
    int c0 = blockIdx.x * 32, r0 = blockIdx.y * 32;
    int x = threadIdx.x;
    int y = threadIdx.y;
    #pragma unroll
    for (int i = y; i < 32; i += 8)
        tile[i][x] = __float2bfloat16(in[(size_t)(r0 + i) * C + c0 + x]);
    __syncthreads();
    #pragma unroll
    for (int i = y; i < 32; i += 8)
        out[(size_t)(c0 + i) * R + r0 + x] = tile[x][i];
}

// ---------- build [Wa|Wb|0] transposed: out bf16 [128][2048] ----------
__global__ __launch_bounds__(256) void build_wab_kernel(
    const float* __restrict__ Wa, const float* __restrict__ Wb, bf16* __restrict__ out)
{
    int k = blockIdx.x * 256 + threadIdx.x;
    int n = blockIdx.y;
    float v = 0.f;
    if (n < 32)      v = Wa[(size_t)k * 32 + n];
    else if (n < 64) v = Wb[(size_t)k * 32 + (n - 32)];
    out[(size_t)n * 2048 + k] = __float2bfloat16(v);
}

// ---------- MFMA GEMM: C[M,N] = A[M,K] * B^T (B given as [N,K]), bf16 in ----------
template <typename OutT>
__global__ __launch_bounds__(256) void gemm_bt_kernel(
    const bf16* __restrict__ A, const bf16* __restrict__ B, OutT* __restrict__ C,
    int M, int N, int K)
{
    __shared__ short sA[128 * 64];
    __shared__ short sB[128 * 64];
    const int tid  = threadIdx.x;
    const int w    = tid >> 6;
    const int lane = tid & 63;
    const int quad = lane >> 4;
    const int r    = lane & 15;
    const int wm   = w >> 1, wn = w & 1;
    const int bm   = blockIdx.x, bn = blockIdx.y;
    const int lrow = lane >> 3;
    const int lp   = lane & 7;
    const int lc   = lp ^ lrow;

    f32x4 acc[4][4] = {};

    const int nkb = K >> 6;
    for (int kb = 0; kb < nkb; ++kb) {
        __syncthreads();
        #pragma unroll
        for (int it = 0; it < 4; ++it) {
            int grp = w * 4 + it;
            int rr  = grp * 8 + lrow;
            const bf16* ga = A + (size_t)(bm * 128 + rr) * K + kb * 64 + lc * 8;
            gload16(ga, (void*)(sA + grp * 512));
            const bf16* gb = B + (size_t)(bn * 128 + rr) * K + kb * 64 + lc * 8;
            gload16(gb, (void*)(sB + grp * 512));
        }
        __syncthreads();

        #pragma unroll
        for (int kk = 0; kk < 2; ++kk) {
            short8 av[4], bv[4];
            #pragma unroll
            for (int i = 0; i < 4; ++i) {
                int p   = (kk * 4 + quad) ^ (r & 7);
                int row = wm * 64 + i * 16 + r;
                av[i] = *(const short8*)(sA + row * 64 + p * 8);
                int rowb = wn * 64 + i * 16 + r;
                bv[i] = *(const short8*)(sB + rowb * 64 + p * 8);
            }
            #pragma unroll
            for (int i = 0; i < 4; ++i)
                #pragma unroll
                for (int j = 0; j < 4; ++j)
                    acc[i][j] = __builtin_amdgcn_mfma_f32_16x16x32_bf16(
                        av[i], bv[j], acc[i][j], 0, 0, 0);
        }
    }

    #pragma unroll
    for (int i = 0; i < 4; ++i) {
        int row0 = bm * 128 + wm * 64 + i * 16 + quad * 4;
        #pragma unroll
        for (int j = 0; j < 4; ++j) {
            int col = bn * 128 + wn * 64 + j * 16 + r;
            #pragma unroll
            for (int e = 0; e < 4; ++e)
                store_c(C, (size_t)(row0 + e) * N + col, acc[i][j][e]);
        }
    }
}

// ---------- conv+silu+l2norm for q,k (fp32 out for the recurrence) ----------
__global__ __launch_bounds__(128) void conv_qk_kernel(
    const bf16* __restrict__ mixed, const float* __restrict__ cq,
    const float* __restrict__ ck, float* __restrict__ qn, float* __restrict__ kn)
{
    int t = blockIdx.x;
    int g = blockIdx.y;
    int d = threadIdx.x;
    int isq = (g < NKV) ? 1 : 0;
    int h   = isq ? g : g - NKV;
    int cl  = h * DKh + d;
    int c   = (isq ? 0 : 2048) + cl;
    const float* cw = isq ? cq : ck;
    float acc = 0.f;
    #pragma unroll
    for (int j = 0; j < 4; ++j) {
        int ts = t - 3 + j;
        if (ts >= 0)
            acc += __bfloat162float(mixed[(size_t)ts * 8192 + c]) * cw[cl * 4 + j];
    }
    float s = acc / (1.f + __expf(-acc));  // silu
    float ss = s * s;
    #pragma unroll
    for (int m = 1; m < 64; m <<= 1) ss += __shfl_xor(ss, m, 64);
    __shared__ float part[2];
    if ((threadIdx.x & 63) == 0) part[threadIdx.x >> 6] = ss;
    __syncthreads();
    float sum = part[0] + part[1];
    float rn = rsqrtf(sum + 1e-6f);
    float outv = s * rn;
    if (isq) outv *= 0.08838834764831845f;   // DK^-0.5 folded into q
    (isq ? qn : kn)[(size_t)t * 2048 + cl] = outv;
}

// ---------- conv+silu for v ----------
__global__ __launch_bounds__(256) void conv_v_kernel(
    const bf16* __restrict__ mixed, const float* __restrict__ cv, bf16* __restrict__ vv)
{
    int idx = blockIdx.x * 256 + threadIdx.x;
    int t = idx >> 12, c = idx & 4095;
    float acc = 0.f;
    #pragma unroll
    for (int j = 0; j < 4; ++j) {
        int ts = t - 3 + j;
        if (ts >= 0)
            acc += __bfloat162float(mixed[(size_t)ts * 8192 + 4096 + c]) * cv[c * 4 + j];
    }
    vv[idx] = __float2bfloat16(acc / (1.f + __expf(-acc)));
}

// ---------- gating ----------
__global__ __launch_bounds__(256) void gating_kernel(
    const float* __restrict__ ab, const float* __restrict__ dt_bias,
    const float* __restrict__ A_log, float* __restrict__ eg, float* __restrict__ beta)
{
    int i = blockIdx.x * 256 + threadIdx.x;
    int t = i >> 5, h = i & 31;
    float a  = ab[(size_t)t * 128 + h] + dt_bias[h];
    float sp = (a <= 20.f) ? log1pf(__expf(a)) : a;
    float gg = -__expf(A_log[h]) * sp;
    eg[i] = __expf(gg);
    float b = ab[(size_t)t * 128 + 32 + h];
    beta[i] = 1.f / (1.f + __expf(-b));
}

// ---------- gated delta-rule recurrence -------------------------------------
// v2: 4 S-elements/thread (was 8) -> 2x threads -> 2 waves/SIMD so dependent
// VALU/DPP/waitcnt latency is hidden by the co-resident wave.
// grid (32 heads, 16 dv-splits), block 256: thread = (dvl=tid>>5, dkl=tid&31)
// owns S[dkl*4..+4][dv]; 32-lane butterfly (4x DPP + ds_swizzle xor16) for
// the DK reductions. Depth-8 register prefetch unchanged.
__device__ __forceinline__ void gdn_step(
    float S[4], const float kf[4], const float qf[4],
    float vc, float egt, float bt, bf16* optr, bool writer)
{
    float t0[4];
    #pragma unroll
    for (int j = 0; j < 4; ++j) t0[j] = S[j] * egt;
    float p0 = t0[0] * kf[0], p1 = t0[1] * kf[1];
    p0 = fmaf(t0[2], kf[2], p0); p1 = fmaf(t0[3], kf[3], p1);
    float kv = red32(p0 + p1);
    float dvv = bt * (vc - kv);
    #pragma unroll
    for (int j = 0; j < 4; ++j) S[j] = fmaf(kf[j], dvv, t0[j]);
    float o0 = qf[0] * S[0], o1 = qf[1] * S[1];
    o0 = fmaf(qf[2], S[2], o0); o1 = fmaf(qf[3], S[3], o1);
    float op = red32(o0 + o1);
    if (writer) *optr = __float2bfloat16(op);
}

#define PF_DEPTH 8

__global__ __launch_bounds__(256) void recur_kernel(
    const float* __restrict__ qn, const float* __restrict__ kn, const bf16* __restrict__ vv,
    const float* __restrict__ egb, const float* __restrict__ betab, bf16* __restrict__ o)
{
    int h   = blockIdx.x;          // 0..31
    int sp  = blockIdx.y;          // 0..15
    int tid = threadIdx.x;
    int dvl = tid >> 5;            // 0..7
    int dkl = tid & 31;            // 0..31 : dk = dkl*4 .. +4
    int dv  = sp * 8 + dvl;
    int hkv = h >> 1;              // GQA repeat-interleave
    bool writer = (dkl == 0);

    const float* kp = kn + hkv * DKh + dkl * 4;
    const float* qp = qn + hkv * DKh + dkl * 4;
    const bf16*  vp = vv + h * DVh + dv;
    const float* ep = egb + h;
    const float* bp = betab + h;
    bf16* optr = o + h * DVh + dv;

    float S[4] = {0.f, 0.f, 0.f, 0.f};

    // prefetch slots (rows t .. t+7). OOB reads (up to 8 rows past each array
    // end) land in the adjacent workspace allocation / pad; values unused.
    float4 ka[PF_DEPTH], qa[PF_DEPTH];
    float  vs[PF_DEPTH], es[PF_DEPTH], bs[PF_DEPTH];
    #pragma unroll
    for (int s = 0; s < PF_DEPTH; ++s) {
        ka[s] = *(const float4*)(kp + (size_t)s * 2048);
        qa[s] = *(const float4*)(qp + (size_t)s * 2048);
        vs[s] = __bfloat162float(vp[(size_t)s * 4096]);
        es[s] = ep[(size_t)s * 32];
        bs[s] = bp[(size_t)s * 32];
    }
    const float* kl = kp + (size_t)PF_DEPTH * 2048;
    const float* ql = qp + (size_t)PF_DEPTH * 2048;
    const bf16*  vl = vp + (size_t)PF_DEPTH * 4096;
    const float* el = ep + (size_t)PF_DEPTH * 32;
    const float* bl = bp + (size_t)PF_DEPTH * 32;

    #pragma unroll 1
    for (int t = 0; t < T_TOK; t += PF_DEPTH) {
        #pragma unroll
        for (int s = 0; s < PF_DEPTH; ++s) {
            float kf[4] = {ka[s].x, ka[s].y, ka[s].z, ka[s].w};
            float qf[4] = {qa[s].x, qa[s].y, qa[s].z, qa[s].w};
            float vc = vs[s], egt = es[s], bt = bs[s];
            // refill slot s with row t+s+PF_DEPTH (pad-covered when OOB)
            ka[s] = *(const float4*)(kl + (size_t)s * 2048);
            qa[s] = *(const float4*)(ql + (size_t)s * 2048);
            vs[s] = __bfloat162float(vl[(size_t)s * 4096]);
            es[s] = el[(size_t)s * 32];
            bs[s] = bl[(size_t)s * 32];
            gdn_step(S, kf, qf, vc, egt, bt, optr + (size_t)(t + s) * 4096, writer);
        }
        kl += (size_t)PF_DEPTH * 2048;
        ql += (size_t)PF_DEPTH * 2048;
        vl += (size_t)PF_DEPTH * 4096;
        el += PF_DEPTH * 32;
        bl += PF_DEPTH * 32;
    }
}

// ---------- gated RMSNorm ----------
__global__ __launch_bounds__(256) void normgate_kernel(
    const bf16* __restrict__ o, const bf16* __restrict__ gate,
    const float* __restrict__ w, bf16* __restrict__ og)
{
    int grp  = blockIdx.x * 4 + (threadIdx.x >> 6);
    int lane = threadIdx.x & 63;
    int t = grp >> 5, h = grp & 31;
    size_t base = (size_t)t * 4096 + h * DVh;
    uint32_t uo = *(const uint32_t*)(o + base + lane * 2);
    float a, b; bf2f(uo, a, b);
    float ss = a * a + b * b;
    #pragma unroll
    for (int m = 1; m < 64; m <<= 1) ss += __shfl_xor(ss, m, 64);
    float rn = rsqrtf(ss * (1.f / 128.f) + 1e-5f);
    uint32_t ug = *(const uint32_t*)(gate + base + lane * 2);
    float ga, gb; bf2f(ug, ga, gb);
    float wa = w[lane * 2], wb = w[lane * 2 + 1];
    float oa = a * rn * wa * (ga / (1.f + __expf(-ga)));
    float ob = b * rn * wb * (gb / (1.f + __expf(-gb)));
    og[base + lane * 2]     = __float2bfloat16(oa);
    og[base + lane * 2 + 1] = __float2bfloat16(ob);
}

// ---------- launch ----------
extern "C" void kernel_launch(void* const* d_in, const int* in_sizes, int n_in,
                              void* d_out, int out_size, void* d_ws, size_t ws_size,
                              hipStream_t stream)
{
    const float* h       = (const float*)d_in[0];
    const float* Wq      = (const float*)d_in[1];
    const float* Wk      = (const float*)d_in[2];
    const float* Wv      = (const float*)d_in[3];
    const float* Wa      = (const float*)d_in[4];
    const float* Wb      = (const float*)d_in[5];
    const float* Wg      = (const float*)d_in[6];
    const float* conv_q  = (const float*)d_in[7];
    const float* conv_k  = (const float*)d_in[8];
    const float* conv_v  = (const float*)d_in[9];
    const float* dt_bias = (const float*)d_in[10];
    const float* A_log   = (const float*)d_in[11];
    const float* onw     = (const float*)d_in[12];
    const float* Wo      = (const float*)d_in[13];
    float* out = (float*)d_out;

    char* ws = (char*)d_ws;
    bf16*  WqkvT = (bf16*)ws;   ws += (size_t)8192 * 2048 * 2;   // 33.5 MB
    bf16*  WgT   = (bf16*)ws;   ws += (size_t)4096 * 2048 * 2;   // 16.8 MB (reused as qnb)
    bf16*  WoT   = (bf16*)ws;   ws += (size_t)2048 * 4096 * 2;   // 16.8 MB
    bf16*  WabT  = (bf16*)ws;   ws += (size_t)128 * 2048 * 2;
    bf16*  hb    = (bf16*)ws;   ws += (size_t)2048 * 2048 * 2;
    bf16*  mixed = (bf16*)ws;   ws += (size_t)2048 * 8192 * 2;   // 33.5 MB
    float* ab    = (float*)ws;  ws += (size_t)2048 * 128 * 4;
    float* knb   = (float*)ws;  ws += (size_t)2048 * 2048 * 4;   // 16.8 MB fp32
    bf16*  vvb   = (bf16*)ws;   ws += (size_t)2048 * 4096 * 2;   // 16.8 MB
    float* eg    = (float*)ws;  ws += (size_t)2048 * 32 * 4;
    float* beta  = (float*)ws;  ws += (size_t)2048 * 32 * 4;
    ws += 32768;                                                 // OOB-prefetch pad
    // aliases over dead regions (stream-ordered lifetimes):
    float* qnb = (float*)WgT;                      // WgT dead after gate GEMM
    bf16*  ob   = WqkvT;                           // WqkvT dead after qkv GEMM
    bf16*  gate = WqkvT + (size_t)2048 * 4096;     // second half of WqkvT region
    bf16*  og   = mixed;                           // mixed dead after conv kernels

    dim3 tb(32, 8);
    transpose_kernel<<<dim3(64, 64),  tb, 0, stream>>>(Wq, WqkvT,                       2048, 2048);
    transpose_kernel<<<dim3(64, 64),  tb, 0, stream>>>(Wk, WqkvT + (size_t)2048 * 2048, 2048, 2048);
    transpose_kernel<<<dim3(128, 64), tb, 0, stream>>>(Wv, WqkvT + (size_t)4096 * 2048, 2048, 4096);
    transpose_kernel<<<dim3(128, 64), tb, 0, stream>>>(Wg, WgT,                         2048, 4096);
    transpose_kernel<<<dim3(64, 128), tb, 0, stream>>>(Wo, WoT,                         4096, 2048);
    build_wab_kernel<<<dim3(8, 128), 256, 0, stream>>>(Wa, Wb, WabT);
    f2b_kernel<<<16384, 256, 0, stream>>>(h, hb, 2048 * 2048);

    gemm_bt_kernel<bf16> <<<dim3(16, 64), 256, 0, stream>>>(hb, WqkvT, mixed, 2048, 8192, 2048);
    gemm_bt_kernel<float><<<dim3(16, 1),  256, 0, stream>>>(hb, WabT,  ab,    2048, 128,  2048);
    gemm_bt_kernel<bf16> <<<dim3(16, 32), 256, 0, stream>>>(hb, WgT,   gate,  2048, 4096, 2048);

    conv_qk_kernel<<<dim3(2048, 32), 128, 0, stream>>>(mixed, conv_q, conv_k, qnb, knb);
    conv_v_kernel<<<32768, 256, 0, stream>>>(mixed, conv_v, vvb);
    gating_kernel<<<256, 256, 0, stream>>>(ab, dt_bias, A_log, eg, beta);

    recur_kernel<<<dim3(32, 16), 256, 0, stream>>>(qnb, knb, vvb, eg, beta, ob);
    normgate_kernel<<<16384, 256, 0, stream>>>(ob, gate, onw, og);

    gemm_bt_kernel<float><<<dim3(16, 16), 256, 0, stream>>>(og, WoT, out, 2048, 2048, 4096);
}

// Round 2
// 985.225 us; speedup vs baseline: 1.3037x; 1.3037x over previous
//
#include <hip/hip_runtime.h>
#include <hip/hip_bf16.h>
#include <stdint.h>
#include <stddef.h>

using bf16 = __hip_bfloat16;
typedef __attribute__((ext_vector_type(8))) short short8;   // 8 bf16 (4 VGPRs)
typedef __attribute__((ext_vector_type(4))) float f32x4;
typedef __attribute__((ext_vector_type(2))) float f32x2;

#define T_TOK 2048
#define HD    2048
#define NH    32
#define NKV   16
#define DKh   128
#define DVh   128

// ---------- helpers ----------
__device__ __forceinline__ void bf2f(uint32_t u, float& a, float& b) {
    union { uint32_t i; float f; } x;
    x.i = u << 16;          a = x.f;
    x.i = u & 0xffff0000u;  b = x.f;
}

__device__ __forceinline__ void gload16(const void* g, void* l) {
    __builtin_amdgcn_global_load_lds(
        (const __attribute__((address_space(1))) void*)g,
        (__attribute__((address_space(3))) void*)l, 16, 0, 0);
}

__device__ __forceinline__ void store_c(bf16* C, size_t off, float v) { C[off] = __float2bfloat16(v); }
__device__ __forceinline__ void store_c(float* C, size_t off, float v) { C[off] = v; }

// DPP butterfly add within rows of 16 lanes (VALU latency, no LDS)
template <int CTRL>
__device__ __forceinline__ float dppadd(float x) {
    int y = __builtin_amdgcn_update_dpp(0, __float_as_int(x), CTRL, 0xf, 0xf, true);
    return x + __int_as_float(y);
}
__device__ __forceinline__ float red16(float x) {
    x = dppadd<0xB1>(x);    // quad_perm [1,0,3,2]  : xor 1
    x = dppadd<0x4E>(x);    // quad_perm [2,3,0,1]  : xor 2
    x = dppadd<0x141>(x);   // row_half_mirror      : xor 4
    x = dppadd<0x140>(x);   // row_mirror           : xor 8
    return x;
}

__device__ __forceinline__ f32x2 pkfma(f32x2 a, f32x2 b, f32x2 c) {
    return __builtin_elementwise_fma(a, b, c);
}

// ---------- convert fp32 -> bf16 elementwise ----------
__global__ __launch_bounds__(256) void f2b_kernel(
    const float* __restrict__ in, bf16* __restrict__ out, int n)
{
    int i = blockIdx.x * 256 + threadIdx.x;
    if (i < n) out[i] = __float2bfloat16(in[i]);
}

// ---------- transpose+convert: in fp32 [R][C] -> out bf16 [C][R] ----------
__global__ __launch_bounds__(256) void transpose_kernel(
    const float* __restrict__ in, bf16* __restrict__ out, int R, int C)
{
    __shared__ bf16 tile[32][33];
    int c0 = blockIdx.x * 32, r0 = blockIdx.y * 32;
    int x = threadIdx.x;
    int y = threadIdx.y;
    #pragma unroll
    for (int i = y; i < 32; i += 8)
        tile[i][x] = __float2bfloat16(in[(size_t)(r0 + i) * C + c0 + x]);
    __syncthreads();
    #pragma unroll
    for (int i = y; i < 32; i += 8)
        out[(size_t)(c0 + i) * R + r0 + x] = tile[x][i];
}

// ---------- build [Wa|Wb|0] transposed: out bf16 [128][2048] ----------
__global__ __launch_bounds__(256) void build_wab_kernel(
    const float* __restrict__ Wa, const float* __restrict__ Wb, bf16* __restrict__ out)
{
    int k = blockIdx.x * 256 + threadIdx.x;
    int n = blockIdx.y;
    float v = 0.f;
    if (n < 32)      v = Wa[(size_t)k * 32 + n];
    else if (n < 64) v = Wb[(size_t)k * 32 + (n - 32)];
    out[(size_t)n * 2048 + k] = __float2bfloat16(v);
}

// ---------- MFMA GEMM: C[M,N] = A[M,K] * B^T (B given as [N,K]), bf16 in ----------
template <typename OutT>
__global__ __launch_bounds__(256) void gemm_bt_kernel(
    const bf16* __restrict__ A, const bf16* __restrict__ B, OutT* __restrict__ C,
    int M, int N, int K)
{
    __shared__ short sA[128 * 64];
    __shared__ short sB[128 * 64];
    const int tid  = threadIdx.x;
    const int w    = tid >> 6;
    const int lane = tid & 63;
    const int quad = lane >> 4;
    const int r    = lane & 15;
    const int wm   = w >> 1, wn = w & 1;
    const int bm   = blockIdx.x, bn = blockIdx.y;
    const int lrow = lane >> 3;
    const int lp   = lane & 7;
    const int lc   = lp ^ lrow;

    f32x4 acc[4][4] = {};

    const int nkb = K >> 6;
    for (int kb = 0; kb < nkb; ++kb) {
        __syncthreads();
        #pragma unroll
        for (int it = 0; it < 4; ++it) {
            int grp = w * 4 + it;
            int rr  = grp * 8 + lrow;
            const bf16* ga = A + (size_t)(bm * 128 + rr) * K + kb * 64 + lc * 8;
            gload16(ga, (void*)(sA + grp * 512));
            const bf16* gb = B + (size_t)(bn * 128 + rr) * K + kb * 64 + lc * 8;
            gload16(gb, (void*)(sB + grp * 512));
        }
        __syncthreads();

        #pragma unroll
        for (int kk = 0; kk < 2; ++kk) {
            short8 av[4], bv[4];
            #pragma unroll
            for (int i = 0; i < 4; ++i) {
                int p   = (kk * 4 + quad) ^ (r & 7);
                int row = wm * 64 + i * 16 + r;
                av[i] = *(const short8*)(sA + row * 64 + p * 8);
                int rowb = wn * 64 + i * 16 + r;
                bv[i] = *(const short8*)(sB + rowb * 64 + p * 8);
            }
            #pragma unroll
            for (int i = 0; i < 4; ++i)
                #pragma unroll
                for (int j = 0; j < 4; ++j)
                    acc[i][j] = __builtin_amdgcn_mfma_f32_16x16x32_bf16(
                        av[i], bv[j], acc[i][j], 0, 0, 0);
        }
    }

    #pragma unroll
    for (int i = 0; i < 4; ++i) {
        int row0 = bm * 128 + wm * 64 + i * 16 + quad * 4;
        #pragma unroll
        for (int j = 0; j < 4; ++j) {
            int col = bn * 128 + wn * 64 + j * 16 + r;
            #pragma unroll
            for (int e = 0; e < 4; ++e)
                store_c(C, (size_t)(row0 + e) * N + col, acc[i][j][e]);
        }
    }
}

// ---------- conv+silu+l2norm for q,k (fp32 out for the recurrence) ----------
__global__ __launch_bounds__(128) void conv_qk_kernel(
    const bf16* __restrict__ mixed, const float* __restrict__ cq,
    const float* __restrict__ ck, float* __restrict__ qn, float* __restrict__ kn)
{
    int t = blockIdx.x;
    int g = blockIdx.y;
    int d = threadIdx.x;
    int isq = (g < NKV) ? 1 : 0;
    int h   = isq ? g : g - NKV;
    int cl  = h * DKh + d;
    int c   = (isq ? 0 : 2048) + cl;
    const float* cw = isq ? cq : ck;
    float acc = 0.f;
    #pragma unroll
    for (int j = 0; j < 4; ++j) {
        int ts = t - 3 + j;
        if (ts >= 0)
            acc += __bfloat162float(mixed[(size_t)ts * 8192 + c]) * cw[cl * 4 + j];
    }
    float s = acc / (1.f + __expf(-acc));  // silu
    float ss = s * s;
    #pragma unroll
    for (int m = 1; m < 64; m <<= 1) ss += __shfl_xor(ss, m, 64);
    __shared__ float part[2];
    if ((threadIdx.x & 63) == 0) part[threadIdx.x >> 6] = ss;
    __syncthreads();
    float sum = part[0] + part[1];
    float rn = rsqrtf(sum + 1e-6f);
    float outv = s * rn;
    if (isq) outv *= 0.08838834764831845f;   // DK^-0.5 folded into q
    (isq ? qn : kn)[(size_t)t * 2048 + cl] = outv;
}

// ---------- conv+silu for v ----------
__global__ __launch_bounds__(256) void conv_v_kernel(
    const bf16* __restrict__ mixed, const float* __restrict__ cv, bf16* __restrict__ vv)
{
    int idx = blockIdx.x * 256 + threadIdx.x;
    int t = idx >> 12, c = idx & 4095;
    float acc = 0.f;
    #pragma unroll
    for (int j = 0; j < 4; ++j) {
        int ts = t - 3 + j;
        if (ts >= 0)
            acc += __bfloat162float(mixed[(size_t)ts * 8192 + 4096 + c]) * cv[c * 4 + j];
    }
    vv[idx] = __float2bfloat16(acc / (1.f + __expf(-acc)));
}

// ---------- gating: interleaved [t][h][{e^g, beta}] for one float2 load ------
__global__ __launch_bounds__(256) void gating_kernel(
    const float* __restrict__ ab, const float* __restrict__ dt_bias,
    const float* __restrict__ A_log, float* __restrict__ egb2)
{
    int i = blockIdx.x * 256 + threadIdx.x;
    int t = i >> 5, h = i & 31;
    float a  = ab[(size_t)t * 128 + h] + dt_bias[h];
    float sp = (a <= 20.f) ? log1pf(__expf(a)) : a;
    float gg = -__expf(A_log[h]) * sp;
    float b = ab[(size_t)t * 128 + 32 + h];
    egb2[(size_t)i * 2]     = __expf(gg);
    egb2[(size_t)i * 2 + 1] = 1.f / (1.f + __expf(-b));
}

// ---------- gated delta-rule recurrence (v3) --------------------------------
// v1 structure (proven 500us): grid (32 heads, 8 dv-splits), block 256,
// thread = (dvl=tid>>4, dkg=tid&15) owns S[dkg*8..+8][dv]; 16-lane DPP
// butterfly (VALU pipe only — ds_swizzle in the chain regressed, round 1).
// v3 changes: packed-fp32 (v_pk_fma_f32) for the 8-wide elementwise work;
// e^g factored OUT of the kv dot (dot starts directly off S); beta*v and
// -beta precomputed at refill so dv = fma(-b, kv, bv) is one chain op;
// e^g/beta loaded as one float2.
__device__ __forceinline__ void gdn_step(
    f32x2 S[4], float4 ka, float4 kb, float4 qa, float4 qb,
    float bvc, float egt, float nbt, bf16* optr, bool writer)
{
    f32x2 k2[4] = {{ka.x, ka.y}, {ka.z, ka.w}, {kb.x, kb.y}, {kb.z, kb.w}};
    f32x2 q2[4] = {{qa.x, qa.y}, {qa.z, qa.w}, {qb.x, qb.y}, {qb.z, qb.w}};
    // kv = e^g * dot(S_old, k)   (e^g uniform scalar -> factored out of dot)
    f32x2 p01 = pkfma(S[1], k2[1], S[0] * k2[0]);
    f32x2 p23 = pkfma(S[3], k2[3], S[2] * k2[2]);
    f32x2 ps  = p01 + p23;
    float kv  = red16(ps.x + ps.y) * egt;
    float dvv = fmaf(nbt, kv, bvc);            // beta*(v - kv)
    f32x2 e2 = {egt, egt}, d2 = {dvv, dvv};
    #pragma unroll
    for (int j = 0; j < 4; ++j) S[j] = pkfma(k2[j], d2, S[j] * e2);
    f32x2 o01 = pkfma(S[1], q2[1], S[0] * q2[0]);
    f32x2 o23 = pkfma(S[3], q2[3], S[2] * q2[2]);
    f32x2 os  = o01 + o23;
    float op  = red16(os.x + os.y);
    if (writer) *optr = __float2bfloat16(op);
}

#define PF_DEPTH 8

__global__ __launch_bounds__(256) void recur_kernel(
    const float* __restrict__ qn, const float* __restrict__ kn, const bf16* __restrict__ vv,
    const float* __restrict__ egb, bf16* __restrict__ o)
{
    int h   = blockIdx.x;          // 0..31
    int sp  = blockIdx.y;          // 0..7
    int tid = threadIdx.x;
    int dvl = tid >> 4;            // 0..15
    int dkg = tid & 15;            // 0..15 : dk = dkg*8 .. +8
    int dv  = sp * 16 + dvl;
    int hkv = h >> 1;              // GQA repeat-interleave
    bool writer = (dkg == 0);

    const float* kp = kn + hkv * DKh + dkg * 8;
    const float* qp = qn + hkv * DKh + dkg * 8;
    const bf16*  vp = vv + h * DVh + dv;
    const float* ep = egb + h * 2;
    bf16* optr = o + h * DVh + dv;

    f32x2 S[4] = {{0.f, 0.f}, {0.f, 0.f}, {0.f, 0.f}, {0.f, 0.f}};

    // prefetch slots (rows t .. t+7). OOB reads (up to 8 rows past each array
    // end) land in the adjacent workspace allocation / pad; values unused.
    float4 ka[PF_DEPTH], kb[PF_DEPTH], qa[PF_DEPTH], qb[PF_DEPTH];
    float  es[PF_DEPTH], nb[PF_DEPTH], bv[PF_DEPTH];
    #pragma unroll
    for (int s = 0; s < PF_DEPTH; ++s) {
        ka[s] = *(const float4*)(kp + (size_t)s * 2048);
        kb[s] = *(const float4*)(kp + (size_t)s * 2048 + 4);
        qa[s] = *(const float4*)(qp + (size_t)s * 2048);
        qb[s] = *(const float4*)(qp + (size_t)s * 2048 + 4);
        float2 eb = *(const float2*)(ep + (size_t)s * 64);
        float vcf = __bfloat162float(vp[(size_t)s * 4096]);
        es[s] = eb.x; nb[s] = -eb.y; bv[s] = eb.y * vcf;
    }
    const float* kl = kp + (size_t)PF_DEPTH * 2048;
    const float* ql = qp + (size_t)PF_DEPTH * 2048;
    const bf16*  vl = vp + (size_t)PF_DEPTH * 4096;
    const float* el = ep + (size_t)PF_DEPTH * 64;

    #pragma unroll 1
    for (int t = 0; t < T_TOK; t += PF_DEPTH) {
        #pragma unroll
        for (int s = 0; s < PF_DEPTH; ++s) {
            float4 kfa = ka[s], kfb = kb[s], qfa = qa[s], qfb = qb[s];
            float egt = es[s], nbt = nb[s], bvc = bv[s];
            // refill slot s with row t+s+PF_DEPTH (pad-covered when OOB)
            ka[s] = *(const float4*)(kl + (size_t)s * 2048);
            kb[s] = *(const float4*)(kl + (size_t)s * 2048 + 4);
            qa[s] = *(const float4*)(ql + (size_t)s * 2048);
            qb[s] = *(const float4*)(ql + (size_t)s * 2048 + 4);
            float2 eb = *(const float2*)(el + (size_t)s * 64);
            float vcf = __bfloat162float(vl[(size_t)s * 4096]);
            es[s] = eb.x; nb[s] = -eb.y; bv[s] = eb.y * vcf;
            gdn_step(S, kfa, kfb, qfa, qfb, bvc, egt, nbt,
                     optr + (size_t)(t + s) * 4096, writer);
        }
        kl += (size_t)PF_DEPTH * 2048;
        ql += (size_t)PF_DEPTH * 2048;
        vl += (size_t)PF_DEPTH * 4096;
        el += (size_t)PF_DEPTH * 64;
    }
}

// ---------- gated RMSNorm ----------
__global__ __launch_bounds__(256) void normgate_kernel(
    const bf16* __restrict__ o, const bf16* __restrict__ gate,
    const float* __restrict__ w, bf16* __restrict__ og)
{
    int grp  = blockIdx.x * 4 + (threadIdx.x >> 6);
    int lane = threadIdx.x & 63;
    int t = grp >> 5, h = grp & 31;
    size_t base = (size_t)t * 4096 + h * DVh;
    uint32_t uo = *(const uint32_t*)(o + base + lane * 2);
    float a, b; bf2f(uo, a, b);
    float ss = a * a + b * b;
    #pragma unroll
    for (int m = 1; m < 64; m <<= 1) ss += __shfl_xor(ss, m, 64);
    float rn = rsqrtf(ss * (1.f / 128.f) + 1e-5f);
    uint32_t ug = *(const uint32_t*)(gate + base + lane * 2);
    float ga, gb; bf2f(ug, ga, gb);
    float wa = w[lane * 2], wb = w[lane * 2 + 1];
    float oa = a * rn * wa * (ga / (1.f + __expf(-ga)));
    float ob = b * rn * wb * (gb / (1.f + __expf(-gb)));
    og[base + lane * 2]     = __float2bfloat16(oa);
    og[base + lane * 2 + 1] = __float2bfloat16(ob);
}

// ---------- launch ----------
extern "C" void kernel_launch(void* const* d_in, const int* in_sizes, int n_in,
                              void* d_out, int out_size, void* d_ws, size_t ws_size,
                              hipStream_t stream)
{
    const float* h       = (const float*)d_in[0];
    const float* Wq      = (const float*)d_in[1];
    const float* Wk      = (const float*)d_in[2];
    const float* Wv      = (const float*)d_in[3];
    const float* Wa      = (const float*)d_in[4];
    const float* Wb      = (const float*)d_in[5];
    const float* Wg      = (const float*)d_in[6];
    const float* conv_q  = (const float*)d_in[7];
    const float* conv_k  = (const float*)d_in[8];
    const float* conv_v  = (const float*)d_in[9];
    const float* dt_bias = (const float*)d_in[10];
    const float* A_log   = (const float*)d_in[11];
    const float* onw     = (const float*)d_in[12];
    const float* Wo      = (const float*)d_in[13];
    float* out = (float*)d_out;

    char* ws = (char*)d_ws;
    bf16*  WqkvT = (bf16*)ws;   ws += (size_t)8192 * 2048 * 2;   // 33.5 MB
    bf16*  WgT   = (bf16*)ws;   ws += (size_t)4096 * 2048 * 2;   // 16.8 MB (reused as qnb)
    bf16*  WoT   = (bf16*)ws;   ws += (size_t)2048 * 4096 * 2;   // 16.8 MB
    bf16*  WabT  = (bf16*)ws;   ws += (size_t)128 * 2048 * 2;
    bf16*  hb    = (bf16*)ws;   ws += (size_t)2048 * 2048 * 2;
    bf16*  mixed = (bf16*)ws;   ws += (size_t)2048 * 8192 * 2;   // 33.5 MB
    float* ab    = (float*)ws;  ws += (size_t)2048 * 128 * 4;
    float* knb   = (float*)ws;  ws += (size_t)2048 * 2048 * 4;   // 16.8 MB fp32
    bf16*  vvb   = (bf16*)ws;   ws += (size_t)2048 * 4096 * 2;   // 16.8 MB
    float* egb2  = (float*)ws;  ws += (size_t)2048 * 64 * 4;     // [t][h][{eg,beta}]
    ws += 32768;                                                 // OOB-prefetch pad
    // aliases over dead regions (stream-ordered lifetimes):
    float* qnb = (float*)WgT;                      // WgT dead after gate GEMM
    bf16*  ob   = WqkvT;                           // WqkvT dead after qkv GEMM
    bf16*  gate = WqkvT + (size_t)2048 * 4096;     // second half of WqkvT region
    bf16*  og   = mixed;                           // mixed dead after conv kernels

    dim3 tb(32, 8);
    transpose_kernel<<<dim3(64, 64),  tb, 0, stream>>>(Wq, WqkvT,                       2048, 2048);
    transpose_kernel<<<dim3(64, 64),  tb, 0, stream>>>(Wk, WqkvT + (size_t)2048 * 2048, 2048, 2048);
    transpose_kernel<<<dim3(128, 64), tb, 0, stream>>>(Wv, WqkvT + (size_t)4096 * 2048, 2048, 4096);
    transpose_kernel<<<dim3(128, 64), tb, 0, stream>>>(Wg, WgT,                         2048, 4096);
    transpose_kernel<<<dim3(64, 128), tb, 0, stream>>>(Wo, WoT,                         4096, 2048);
    build_wab_kernel<<<dim3(8, 128), 256, 0, stream>>>(Wa, Wb, WabT);
    f2b_kernel<<<16384, 256, 0, stream>>>(h, hb, 2048 * 2048);

    gemm_bt_kernel<bf16> <<<dim3(16, 64), 256, 0, stream>>>(hb, WqkvT, mixed, 2048, 8192, 2048);
    gemm_bt_kernel<float><<<dim3(16, 1),  256, 0, stream>>>(hb, WabT,  ab,    2048, 128,  2048);
    gemm_bt_kernel<bf16> <<<dim3(16, 32), 256, 0, stream>>>(hb, WgT,   gate,  2048, 4096, 2048);

    conv_qk_kernel<<<dim3(2048, 32), 128, 0, stream>>>(mixed, conv_q, conv_k, qnb, knb);
    conv_v_kernel<<<32768, 256, 0, stream>>>(mixed, conv_v, vvb);
    gating_kernel<<<256, 256, 0, stream>>>(ab, dt_bias, A_log, egb2);

    recur_kernel<<<dim3(32, 8), 256, 0, stream>>>(qnb, knb, vvb, egb2, ob);
    normgate_kernel<<<16384, 256, 0, stream>>>(ob, gate, onw, og);

    gemm_bt_kernel<float><<<dim3(16, 16), 256, 0, stream>>>(og, WoT, out, 2048, 2048, 4096);
}

// Round 3
// 978.437 us; speedup vs baseline: 1.3128x; 1.0069x over previous
//
#include <hip/hip_runtime.h>
#include <hip/hip_bf16.h>
#include <stdint.h>
#include <stddef.h>

using bf16 = __hip_bfloat16;
typedef __attribute__((ext_vector_type(8))) short short8;   // 8 bf16 (4 VGPRs)
typedef __attribute__((ext_vector_type(4))) float f32x4;
typedef __attribute__((ext_vector_type(2))) float f32x2;

#define T_TOK 2048
#define HD    2048
#define NH    32
#define NKV   16
#define DKh   128
#define DVh   128

// ---------- helpers ----------
__device__ __forceinline__ void bf2f(uint32_t u, float& a, float& b) {
    union { uint32_t i; float f; } x;
    x.i = u << 16;          a = x.f;
    x.i = u & 0xffff0000u;  b = x.f;
}

__device__ __forceinline__ void gload16(const void* g, void* l) {
    __builtin_amdgcn_global_load_lds(
        (const __attribute__((address_space(1))) void*)g,
        (__attribute__((address_space(3))) void*)l, 16, 0, 0);
}

__device__ __forceinline__ void store_c(bf16* C, size_t off, float v) { C[off] = __float2bfloat16(v); }
__device__ __forceinline__ void store_c(float* C, size_t off, float v) { C[off] = v; }

// DPP butterfly add within rows of 16 lanes (VALU latency, no LDS)
template <int CTRL>
__device__ __forceinline__ float dppadd(float x) {
    int y = __builtin_amdgcn_update_dpp(0, __float_as_int(x), CTRL, 0xf, 0xf, true);
    return x + __int_as_float(y);
}
__device__ __forceinline__ float red16(float x) {
    x = dppadd<0xB1>(x);    // quad_perm [1,0,3,2]  : xor 1
    x = dppadd<0x4E>(x);    // quad_perm [2,3,0,1]  : xor 2
    x = dppadd<0x141>(x);   // row_half_mirror      : xor 4
    x = dppadd<0x140>(x);   // row_mirror           : xor 8
    return x;
}

__device__ __forceinline__ f32x2 pkfma(f32x2 a, f32x2 b, f32x2 c) {
    return __builtin_elementwise_fma(a, b, c);
}

// ---------- convert fp32 -> bf16 elementwise ----------
__global__ __launch_bounds__(256) void f2b_kernel(
    const float* __restrict__ in, bf16* __restrict__ out, int n)
{
    int i = blockIdx.x * 256 + threadIdx.x;
    if (i < n) out[i] = __float2bfloat16(in[i]);
}

// ---------- transpose+convert: in fp32 [R][C] -> out bf16 [C][R] ----------
__global__ __launch_bounds__(256) void transpose_kernel(
    const float* __restrict__ in, bf16* __restrict__ out, int R, int C)
{
    __shared__ bf16 tile[32][33];
    int c0 = blockIdx.x * 32, r0 = blockIdx.y * 32;
    int x = threadIdx.x;
    int y = threadIdx.y;
    #pragma unroll
    for (int i = y; i < 32; i += 8)
        tile[i][x] = __float2bfloat16(in[(size_t)(r0 + i) * C + c0 + x]);
    __syncthreads();
    #pragma unroll
    for (int i = y; i < 32; i += 8)
        out[(size_t)(c0 + i) * R + r0 + x] = tile[x][i];
}

// ---------- build [Wa|Wb|0] transposed: out bf16 [128][2048] ----------
__global__ __launch_bounds__(256) void build_wab_kernel(
    const float* __restrict__ Wa, const float* __restrict__ Wb, bf16* __restrict__ out)
{
    int k = blockIdx.x * 256 + threadIdx.x;
    int n = blockIdx.y;
    float v = 0.f;
    if (n < 32)      v = Wa[(size_t)k * 32 + n];
    else if (n < 64) v = Wb[(size_t)k * 32 + (n - 32)];
    out[(size_t)n * 2048 + k] = __float2bfloat16(v);
}

// ---------- MFMA GEMM: C[M,N] = A[M,K] * B^T (B given as [N,K]), bf16 in ----------
template <typename OutT>
__global__ __launch_bounds__(256) void gemm_bt_kernel(
    const bf16* __restrict__ A, const bf16* __restrict__ B, OutT* __restrict__ C,
    int M, int N, int K)
{
    __shared__ short sA[128 * 64];
    __shared__ short sB[128 * 64];
    const int tid  = threadIdx.x;
    const int w    = tid >> 6;
    const int lane = tid & 63;
    const int quad = lane >> 4;
    const int r    = lane & 15;
    const int wm   = w >> 1, wn = w & 1;
    const int bm   = blockIdx.x, bn = blockIdx.y;
    const int lrow = lane >> 3;
    const int lp   = lane & 7;
    const int lc   = lp ^ lrow;

    f32x4 acc[4][4] = {};

    const int nkb = K >> 6;
    for (int kb = 0; kb < nkb; ++kb) {
        __syncthreads();
        #pragma unroll
        for (int it = 0; it < 4; ++it) {
            int grp = w * 4 + it;
            int rr  = grp * 8 + lrow;
            const bf16* ga = A + (size_t)(bm * 128 + rr) * K + kb * 64 + lc * 8;
            gload16(ga, (void*)(sA + grp * 512));
            const bf16* gb = B + (size_t)(bn * 128 + rr) * K + kb * 64 + lc * 8;
            gload16(gb, (void*)(sB + grp * 512));
        }
        __syncthreads();

        #pragma unroll
        for (int kk = 0; kk < 2; ++kk) {
            short8 av[4], bv[4];
            #pragma unroll
            for (int i = 0; i < 4; ++i) {
                int p   = (kk * 4 + quad) ^ (r & 7);
                int row = wm * 64 + i * 16 + r;
                av[i] = *(const short8*)(sA + row * 64 + p * 8);
                int rowb = wn * 64 + i * 16 + r;
                bv[i] = *(const short8*)(sB + rowb * 64 + p * 8);
            }
            #pragma unroll
            for (int i = 0; i < 4; ++i)
                #pragma unroll
                for (int j = 0; j < 4; ++j)
                    acc[i][j] = __builtin_amdgcn_mfma_f32_16x16x32_bf16(
                        av[i], bv[j], acc[i][j], 0, 0, 0);
        }
    }

    #pragma unroll
    for (int i = 0; i < 4; ++i) {
        int row0 = bm * 128 + wm * 64 + i * 16 + quad * 4;
        #pragma unroll
        for (int j = 0; j < 4; ++j) {
            int col = bn * 128 + wn * 64 + j * 16 + r;
            #pragma unroll
            for (int e = 0; e < 4; ++e)
                store_c(C, (size_t)(row0 + e) * N + col, acc[i][j][e]);
        }
    }
}

// ---------- conv+silu+l2norm for q,k (fp32 out for the recurrence) ----------
__global__ __launch_bounds__(128) void conv_qk_kernel(
    const bf16* __restrict__ mixed, const float* __restrict__ cq,
    const float* __restrict__ ck, float* __restrict__ qn, float* __restrict__ kn)
{
    int t = blockIdx.x;
    int g = blockIdx.y;
    int d = threadIdx.x;
    int isq = (g < NKV) ? 1 : 0;
    int h   = isq ? g : g - NKV;
    int cl  = h * DKh + d;
    int c   = (isq ? 0 : 2048) + cl;
    const float* cw = isq ? cq : ck;
    float acc = 0.f;
    #pragma unroll
    for (int j = 0; j < 4; ++j) {
        int ts = t - 3 + j;
        if (ts >= 0)
            acc += __bfloat162float(mixed[(size_t)ts * 8192 + c]) * cw[cl * 4 + j];
    }
    float s = acc / (1.f + __expf(-acc));  // silu
    float ss = s * s;
    #pragma unroll
    for (int m = 1; m < 64; m <<= 1) ss += __shfl_xor(ss, m, 64);
    __shared__ float part[2];
    if ((threadIdx.x & 63) == 0) part[threadIdx.x >> 6] = ss;
    __syncthreads();
    float sum = part[0] + part[1];
    float rn = rsqrtf(sum + 1e-6f);
    float outv = s * rn;
    if (isq) outv *= 0.08838834764831845f;   // DK^-0.5 folded into q
    (isq ? qn : kn)[(size_t)t * 2048 + cl] = outv;
}

// ---------- conv+silu for v ----------
__global__ __launch_bounds__(256) void conv_v_kernel(
    const bf16* __restrict__ mixed, const float* __restrict__ cv, bf16* __restrict__ vv)
{
    int idx = blockIdx.x * 256 + threadIdx.x;
    int t = idx >> 12, c = idx & 4095;
    float acc = 0.f;
    #pragma unroll
    for (int j = 0; j < 4; ++j) {
        int ts = t - 3 + j;
        if (ts >= 0)
            acc += __bfloat162float(mixed[(size_t)ts * 8192 + 4096 + c]) * cv[c * 4 + j];
    }
    vv[idx] = __float2bfloat16(acc / (1.f + __expf(-acc)));
}

// ---------- gating: interleaved [t][h][{e^g, beta}] for one float2 load ------
__global__ __launch_bounds__(256) void gating_kernel(
    const float* __restrict__ ab, const float* __restrict__ dt_bias,
    const float* __restrict__ A_log, float* __restrict__ egb2)
{
    int i = blockIdx.x * 256 + threadIdx.x;
    int t = i >> 5, h = i & 31;
    float a  = ab[(size_t)t * 128 + h] + dt_bias[h];
    float sp = (a <= 20.f) ? log1pf(__expf(a)) : a;
    float gg = -__expf(A_log[h]) * sp;
    float b = ab[(size_t)t * 128 + 32 + h];
    egb2[(size_t)i * 2]     = __expf(gg);
    egb2[(size_t)i * 2 + 1] = 1.f / (1.f + __expf(-b));
}

// ---------- gated delta-rule recurrence (v4) --------------------------------
// v3 structure (455us): grid (32 heads, 8 dv-splits), block 256, thread =
// (dvl=tid>>4, dkg=tid&15) owns S[dkg*8..+8][dv]; 16-lane DPP butterfly;
// packed fp32; e^g factored out of kv dot; beta*v/-beta precomputed.
// v4 change: __launch_bounds__(256, 1). At default bounds the allocator
// capped at 108 VGPR (2-wave-capable) — but depth-8 prefetch needs ~180, so
// the compiler sank refill loads toward their uses, collapsing the pipeline
// and exposing an L1/L2 round-trip per step (~320 of 533 cy). Occupancy is
// structurally 1 wave/SIMD (256 blocks = 1 block/CU), so raising the VGPR
// cap is free and lets all 8 slots stay register-resident.
__device__ __forceinline__ void gdn_step(
    f32x2 S[4], float4 ka, float4 kb, float4 qa, float4 qb,
    float bvc, float egt, float nbt, bf16* optr, bool writer)
{
    f32x2 k2[4] = {{ka.x, ka.y}, {ka.z, ka.w}, {kb.x, kb.y}, {kb.z, kb.w}};
    f32x2 q2[4] = {{qa.x, qa.y}, {qa.z, qa.w}, {qb.x, qb.y}, {qb.z, qb.w}};
    // kv = e^g * dot(S_old, k)   (e^g uniform scalar -> factored out of dot)
    f32x2 p01 = pkfma(S[1], k2[1], S[0] * k2[0]);
    f32x2 p23 = pkfma(S[3], k2[3], S[2] * k2[2]);
    f32x2 ps  = p01 + p23;
    float kv  = red16(ps.x + ps.y) * egt;
    float dvv = fmaf(nbt, kv, bvc);            // beta*(v - kv)
    f32x2 e2 = {egt, egt}, d2 = {dvv, dvv};
    #pragma unroll
    for (int j = 0; j < 4; ++j) S[j] = pkfma(k2[j], d2, S[j] * e2);
    f32x2 o01 = pkfma(S[1], q2[1], S[0] * q2[0]);
    f32x2 o23 = pkfma(S[3], q2[3], S[2] * q2[2]);
    f32x2 os  = o01 + o23;
    float op  = red16(os.x + os.y);
    if (writer) *optr = __float2bfloat16(op);
}

#define PF_DEPTH 8

__global__ __launch_bounds__(256, 1) void recur_kernel(
    const float* __restrict__ qn, const float* __restrict__ kn, const bf16* __restrict__ vv,
    const float* __restrict__ egb, bf16* __restrict__ o)
{
    int h   = blockIdx.x;          // 0..31
    int sp  = blockIdx.y;          // 0..7
    int tid = threadIdx.x;
    int dvl = tid >> 4;            // 0..15
    int dkg = tid & 15;            // 0..15 : dk = dkg*8 .. +8
    int dv  = sp * 16 + dvl;
    int hkv = h >> 1;              // GQA repeat-interleave
    bool writer = (dkg == 0);

    const float* kp = kn + hkv * DKh + dkg * 8;
    const float* qp = qn + hkv * DKh + dkg * 8;
    const bf16*  vp = vv + h * DVh + dv;
    const float* ep = egb + h * 2;
    bf16* optr = o + h * DVh + dv;

    f32x2 S[4] = {{0.f, 0.f}, {0.f, 0.f}, {0.f, 0.f}, {0.f, 0.f}};

    // prefetch slots (rows t .. t+7). OOB reads (up to 8 rows past each array
    // end) land in the adjacent workspace allocation / pad; values unused.
    float4 ka[PF_DEPTH], kb[PF_DEPTH], qa[PF_DEPTH], qb[PF_DEPTH];
    float  es[PF_DEPTH], nb[PF_DEPTH], bv[PF_DEPTH];
    #pragma unroll
    for (int s = 0; s < PF_DEPTH; ++s) {
        ka[s] = *(const float4*)(kp + (size_t)s * 2048);
        kb[s] = *(const float4*)(kp + (size_t)s * 2048 + 4);
        qa[s] = *(const float4*)(qp + (size_t)s * 2048);
        qb[s] = *(const float4*)(qp + (size_t)s * 2048 + 4);
        float2 eb = *(const float2*)(ep + (size_t)s * 64);
        float vcf = __bfloat162float(vp[(size_t)s * 4096]);
        es[s] = eb.x; nb[s] = -eb.y; bv[s] = eb.y * vcf;
    }
    const float* kl = kp + (size_t)PF_DEPTH * 2048;
    const float* ql = qp + (size_t)PF_DEPTH * 2048;
    const bf16*  vl = vp + (size_t)PF_DEPTH * 4096;
    const float* el = ep + (size_t)PF_DEPTH * 64;

    #pragma unroll 1
    for (int t = 0; t < T_TOK; t += PF_DEPTH) {
        #pragma unroll
        for (int s = 0; s < PF_DEPTH; ++s) {
            float4 kfa = ka[s], kfb = kb[s], qfa = qa[s], qfb = qb[s];
            float egt = es[s], nbt = nb[s], bvc = bv[s];
            // refill slot s with row t+s+PF_DEPTH (pad-covered when OOB)
            ka[s] = *(const float4*)(kl + (size_t)s * 2048);
            kb[s] = *(const float4*)(kl + (size_t)s * 2048 + 4);
            qa[s] = *(const float4*)(ql + (size_t)s * 2048);
            qb[s] = *(const float4*)(ql + (size_t)s * 2048 + 4);
            float2 eb = *(const float2*)(el + (size_t)s * 64);
            float vcf = __bfloat162float(vl[(size_t)s * 4096]);
            es[s] = eb.x; nb[s] = -eb.y; bv[s] = eb.y * vcf;
            gdn_step(S, kfa, kfb, qfa, qfb, bvc, egt, nbt,
                     optr + (size_t)(t + s) * 4096, writer);
        }
        kl += (size_t)PF_DEPTH * 2048;
        ql += (size_t)PF_DEPTH * 2048;
        vl += (size_t)PF_DEPTH * 4096;
        el += (size_t)PF_DEPTH * 64;
    }
}

// ---------- gated RMSNorm ----------
__global__ __launch_bounds__(256) void normgate_kernel(
    const bf16* __restrict__ o, const bf16* __restrict__ gate,
    const float* __restrict__ w, bf16* __restrict__ og)
{
    int grp  = blockIdx.x * 4 + (threadIdx.x >> 6);
    int lane = threadIdx.x & 63;
    int t = grp >> 5, h = grp & 31;
    size_t base = (size_t)t * 4096 + h * DVh;
    uint32_t uo = *(const uint32_t*)(o + base + lane * 2);
    float a, b; bf2f(uo, a, b);
    float ss = a * a + b * b;
    #pragma unroll
    for (int m = 1; m < 64; m <<= 1) ss += __shfl_xor(ss, m, 64);
    float rn = rsqrtf(ss * (1.f / 128.f) + 1e-5f);
    uint32_t ug = *(const uint32_t*)(gate + base + lane * 2);
    float ga, gb; bf2f(ug, ga, gb);
    float wa = w[lane * 2], wb = w[lane * 2 + 1];
    float oa = a * rn * wa * (ga / (1.f + __expf(-ga)));
    float ob = b * rn * wb * (gb / (1.f + __expf(-gb)));
    og[base + lane * 2]     = __float2bfloat16(oa);
    og[base + lane * 2 + 1] = __float2bfloat16(ob);
}

// ---------- launch ----------
extern "C" void kernel_launch(void* const* d_in, const int* in_sizes, int n_in,
                              void* d_out, int out_size, void* d_ws, size_t ws_size,
                              hipStream_t stream)
{
    const float* h       = (const float*)d_in[0];
    const float* Wq      = (const float*)d_in[1];
    const float* Wk      = (const float*)d_in[2];
    const float* Wv      = (const float*)d_in[3];
    const float* Wa      = (const float*)d_in[4];
    const float* Wb      = (const float*)d_in[5];
    const float* Wg      = (const float*)d_in[6];
    const float* conv_q  = (const float*)d_in[7];
    const float* conv_k  = (const float*)d_in[8];
    const float* conv_v  = (const float*)d_in[9];
    const float* dt_bias = (const float*)d_in[10];
    const float* A_log   = (const float*)d_in[11];
    const float* onw     = (const float*)d_in[12];
    const float* Wo      = (const float*)d_in[13];
    float* out = (float*)d_out;

    char* ws = (char*)d_ws;
    bf16*  WqkvT = (bf16*)ws;   ws += (size_t)8192 * 2048 * 2;   // 33.5 MB
    bf16*  WgT   = (bf16*)ws;   ws += (size_t)4096 * 2048 * 2;   // 16.8 MB (reused as qnb)
    bf16*  WoT   = (bf16*)ws;   ws += (size_t)2048 * 4096 * 2;   // 16.8 MB
    bf16*  WabT  = (bf16*)ws;   ws += (size_t)128 * 2048 * 2;
    bf16*  hb    = (bf16*)ws;   ws += (size_t)2048 * 2048 * 2;
    bf16*  mixed = (bf16*)ws;   ws += (size_t)2048 * 8192 * 2;   // 33.5 MB
    float* ab    = (float*)ws;  ws += (size_t)2048 * 128 * 4;
    float* knb   = (float*)ws;  ws += (size_t)2048 * 2048 * 4;   // 16.8 MB fp32
    bf16*  vvb   = (bf16*)ws;   ws += (size_t)2048 * 4096 * 2;   // 16.8 MB
    float* egb2  = (float*)ws;  ws += (size_t)2048 * 64 * 4;     // [t][h][{eg,beta}]
    ws += 32768;                                                 // OOB-prefetch pad
    // aliases over dead regions (stream-ordered lifetimes):
    float* qnb = (float*)WgT;                      // WgT dead after gate GEMM
    bf16*  ob   = WqkvT;                           // WqkvT dead after qkv GEMM
    bf16*  gate = WqkvT + (size_t)2048 * 4096;     // second half of WqkvT region
    bf16*  og   = mixed;                           // mixed dead after conv kernels

    dim3 tb(32, 8);
    transpose_kernel<<<dim3(64, 64),  tb, 0, stream>>>(Wq, WqkvT,                       2048, 2048);
    transpose_kernel<<<dim3(64, 64),  tb, 0, stream>>>(Wk, WqkvT + (size_t)2048 * 2048, 2048, 2048);
    transpose_kernel<<<dim3(128, 64), tb, 0, stream>>>(Wv, WqkvT + (size_t)4096 * 2048, 2048, 4096);
    transpose_kernel<<<dim3(128, 64), tb, 0, stream>>>(Wg, WgT,                         2048, 4096);
    transpose_kernel<<<dim3(64, 128), tb, 0, stream>>>(Wo, WoT,                         4096, 2048);
    build_wab_kernel<<<dim3(8, 128), 256, 0, stream>>>(Wa, Wb, WabT);
    f2b_kernel<<<16384, 256, 0, stream>>>(h, hb, 2048 * 2048);

    gemm_bt_kernel<bf16> <<<dim3(16, 64), 256, 0, stream>>>(hb, WqkvT, mixed, 2048, 8192, 2048);
    gemm_bt_kernel<float><<<dim3(16, 1),  256, 0, stream>>>(hb, WabT,  ab,    2048, 128,  2048);
    gemm_bt_kernel<bf16> <<<dim3(16, 32), 256, 0, stream>>>(hb, WgT,   gate,  2048, 4096, 2048);

    conv_qk_kernel<<<dim3(2048, 32), 128, 0, stream>>>(mixed, conv_q, conv_k, qnb, knb);
    conv_v_kernel<<<32768, 256, 0, stream>>>(mixed, conv_v, vvb);
    gating_kernel<<<256, 256, 0, stream>>>(ab, dt_bias, A_log, egb2);

    recur_kernel<<<dim3(32, 8), 256, 0, stream>>>(qnb, knb, vvb, egb2, ob);
    normgate_kernel<<<16384, 256, 0, stream>>>(ob, gate, onw, og);

    gemm_bt_kernel<float><<<dim3(16, 16), 256, 0, stream>>>(og, WoT, out, 2048, 2048, 4096);
}

// Round 5
// 960.422 us; speedup vs baseline: 1.3374x; 1.0188x over previous
//
#include <hip/hip_runtime.h>
#include <hip/hip_bf16.h>
#include <stdint.h>
#include <stddef.h>

using bf16 = __hip_bfloat16;
typedef __attribute__((ext_vector_type(8))) short short8;   // 8 bf16 (4 VGPRs)
typedef __attribute__((ext_vector_type(4))) float f32x4;
typedef __attribute__((ext_vector_type(2))) float f32x2;

#define T_TOK 2048
#define HD    2048
#define NH    32
#define NKV   16
#define DKh   128
#define DVh   128

// ---------- helpers ----------
__device__ __forceinline__ void bf2f(uint32_t u, float& a, float& b) {
    union { uint32_t i; float f; } x;
    x.i = u << 16;          a = x.f;
    x.i = u & 0xffff0000u;  b = x.f;
}

__device__ __forceinline__ void gload16(const void* g, void* l) {
    __builtin_amdgcn_global_load_lds(
        (const __attribute__((address_space(1))) void*)g,
        (__attribute__((address_space(3))) void*)l, 16, 0, 0);
}

__device__ __forceinline__ void store_c(bf16* C, size_t off, float v) { C[off] = __float2bfloat16(v); }
__device__ __forceinline__ void store_c(float* C, size_t off, float v) { C[off] = v; }

// DPP butterfly add within rows of 16 lanes (VALU latency, no LDS)
template <int CTRL>
__device__ __forceinline__ float dppadd(float x) {
    int y = __builtin_amdgcn_update_dpp(0, __float_as_int(x), CTRL, 0xf, 0xf, true);
    return x + __int_as_float(y);
}
// dual interleaved 16-lane butterfly: two independent DPP chains pipeline,
// ~1 chain of latency for 2 reductions.
__device__ __forceinline__ void red16x2(float& x, float& y) {
    x = dppadd<0xB1>(x);  y = dppadd<0xB1>(y);    // xor 1
    x = dppadd<0x4E>(x);  y = dppadd<0x4E>(y);    // xor 2
    x = dppadd<0x141>(x); y = dppadd<0x141>(y);   // xor 4
    x = dppadd<0x140>(x); y = dppadd<0x140>(y);   // xor 8
}

__device__ __forceinline__ f32x2 pkfma(f32x2 a, f32x2 b, f32x2 c) {
    return __builtin_elementwise_fma(a, b, c);
}

// ---------- convert fp32 -> bf16 elementwise ----------
__global__ __launch_bounds__(256) void f2b_kernel(
    const float* __restrict__ in, bf16* __restrict__ out, int n)
{
    int i = blockIdx.x * 256 + threadIdx.x;
    if (i < n) out[i] = __float2bfloat16(in[i]);
}

// ---------- transpose+convert: in fp32 [R][C] -> out bf16 [C][R] ----------
__global__ __launch_bounds__(256) void transpose_kernel(
    const float* __restrict__ in, bf16* __restrict__ out, int R, int C)
{
    __shared__ bf16 tile[32][33];
    int c0 = blockIdx.x * 32, r0 = blockIdx.y * 32;
    int x = threadIdx.x;
    int y = threadIdx.y;
    #pragma unroll
    for (int i = y; i < 32; i += 8)
        tile[i][x] = __float2bfloat16(in[(size_t)(r0 + i) * C + c0 + x]);
    __syncthreads();
    #pragma unroll
    for (int i = y; i < 32; i += 8)
        out[(size_t)(c0 + i) * R + r0 + x] = tile[x][i];
}

// ---------- build [Wa|Wb|0] transposed: out bf16 [128][2048] ----------
__global__ __launch_bounds__(256) void build_wab_kernel(
    const float* __restrict__ Wa, const float* __restrict__ Wb, bf16* __restrict__ out)
{
    int k = blockIdx.x * 256 + threadIdx.x;
    int n = blockIdx.y;
    float v = 0.f;
    if (n < 32)      v = Wa[(size_t)k * 32 + n];
    else if (n < 64) v = Wb[(size_t)k * 32 + (n - 32)];
    out[(size_t)n * 2048 + k] = __float2bfloat16(v);
}

// ---------- MFMA GEMM: C[M,N] = A[M,K] * B^T (B given as [N,K]), bf16 in ----------
template <typename OutT>
__global__ __launch_bounds__(256) void gemm_bt_kernel(
    const bf16* __restrict__ A, const bf16* __restrict__ B, OutT* __restrict__ C,
    int M, int N, int K)
{
    __shared__ short sA[128 * 64];
    __shared__ short sB[128 * 64];
    const int tid  = threadIdx.x;
    const int w    = tid >> 6;
    const int lane = tid & 63;
    const int quad = lane >> 4;
    const int r    = lane & 15;
    const int wm   = w >> 1, wn = w & 1;
    const int bm   = blockIdx.x, bn = blockIdx.y;
    const int lrow = lane >> 3;
    const int lp   = lane & 7;
    const int lc   = lp ^ lrow;

    f32x4 acc[4][4] = {};

    const int nkb = K >> 6;
    for (int kb = 0; kb < nkb; ++kb) {
        __syncthreads();
        #pragma unroll
        for (int it = 0; it < 4; ++it) {
            int grp = w * 4 + it;
            int rr  = grp * 8 + lrow;
            const bf16* ga = A + (size_t)(bm * 128 + rr) * K + kb * 64 + lc * 8;
            gload16(ga, (void*)(sA + grp * 512));
            const bf16* gb = B + (size_t)(bn * 128 + rr) * K + kb * 64 + lc * 8;
            gload16(gb, (void*)(sB + grp * 512));
        }
        __syncthreads();

        #pragma unroll
        for (int kk = 0; kk < 2; ++kk) {
            short8 av[4], bv[4];
            #pragma unroll
            for (int i = 0; i < 4; ++i) {
                int p   = (kk * 4 + quad) ^ (r & 7);
                int row = wm * 64 + i * 16 + r;
                av[i] = *(const short8*)(sA + row * 64 + p * 8);
                int rowb = wn * 64 + i * 16 + r;
                bv[i] = *(const short8*)(sB + rowb * 64 + p * 8);
            }
            #pragma unroll
            for (int i = 0; i < 4; ++i)
                #pragma unroll
                for (int j = 0; j < 4; ++j)
                    acc[i][j] = __builtin_amdgcn_mfma_f32_16x16x32_bf16(
                        av[i], bv[j], acc[i][j], 0, 0, 0);
        }
    }

    #pragma unroll
    for (int i = 0; i < 4; ++i) {
        int row0 = bm * 128 + wm * 64 + i * 16 + quad * 4;
        #pragma unroll
        for (int j = 0; j < 4; ++j) {
            int col = bn * 128 + wn * 64 + j * 16 + r;
            #pragma unroll
            for (int e = 0; e < 4; ++e)
                store_c(C, (size_t)(row0 + e) * N + col, acc[i][j][e]);
        }
    }
}

// ---------- conv+silu+l2norm for q AND k (one block per (t,hkv)) ------------
// Also computes qk[t][hkv] = qn . kn (post-norm, incl. DK^-0.5) and writes it
// into lane 3 of the packed gate buffer pk4[t][h][4] for both GQA heads.
__global__ __launch_bounds__(128) void conv_qk_kernel(
    const bf16* __restrict__ mixed, const float* __restrict__ cq,
    const float* __restrict__ ck, float* __restrict__ qn, float* __restrict__ kn,
    float* __restrict__ pk4)
{
    int t   = blockIdx.x;
    int hkv = blockIdx.y;
    int d   = threadIdx.x;
    int cl  = hkv * DKh + d;
    float aq = 0.f, ak = 0.f;
    #pragma unroll
    for (int j = 0; j < 4; ++j) {
        int ts = t - 3 + j;
        if (ts >= 0) {
            aq += __bfloat162float(mixed[(size_t)ts * 8192 + cl])        * cq[cl * 4 + j];
            ak += __bfloat162float(mixed[(size_t)ts * 8192 + 2048 + cl]) * ck[cl * 4 + j];
        }
    }
    float sq = aq / (1.f + __expf(-aq));   // silu
    float sk = ak / (1.f + __expf(-ak));
    float s0 = sq * sq, s1 = sk * sk, s2 = sq * sk;
    #pragma unroll
    for (int m = 1; m < 64; m <<= 1) {
        s0 += __shfl_xor(s0, m, 64);
        s1 += __shfl_xor(s1, m, 64);
        s2 += __shfl_xor(s2, m, 64);
    }
    __shared__ float part[6];
    if ((threadIdx.x & 63) == 0) {
        int w = threadIdx.x >> 6;
        part[w * 3 + 0] = s0; part[w * 3 + 1] = s1; part[w * 3 + 2] = s2;
    }
    __syncthreads();
    float sumq = part[0] + part[3];
    float sumk = part[1] + part[4];
    float sqk  = part[2] + part[5];
    float rnq = rsqrtf(sumq + 1e-6f);
    float rnk = rsqrtf(sumk + 1e-6f);
    const float scale = 0.08838834764831845f;           // DK^-0.5 folded into q
    qn[(size_t)t * 2048 + cl] = sq * rnq * scale;
    kn[(size_t)t * 2048 + cl] = sk * rnk;
    if (d == 0) {
        float qk = sqk * rnq * rnk * scale;             // qn . kn
        pk4[((size_t)t * 32 + 2 * hkv)     * 4 + 3] = qk;
        pk4[((size_t)t * 32 + 2 * hkv + 1) * 4 + 3] = qk;
    }
}

// ---------- conv+silu for v ----------
__global__ __launch_bounds__(256) void conv_v_kernel(
    const bf16* __restrict__ mixed, const float* __restrict__ cv, bf16* __restrict__ vv)
{
    int idx = blockIdx.x * 256 + threadIdx.x;
    int t = idx >> 12, c = idx & 4095;
    float acc = 0.f;
    #pragma unroll
    for (int j = 0; j < 4; ++j) {
        int ts = t - 3 + j;
        if (ts >= 0)
            acc += __bfloat162float(mixed[(size_t)ts * 8192 + 4096 + c]) * cv[c * 4 + j];
    }
    vv[idx] = __float2bfloat16(acc / (1.f + __expf(-acc)));
}

// ---------- gating: pack [t][h][{e^g, -beta*e^g, beta, (qk)}] ----------------
// lane 3 (qk) is written by conv_qk_kernel — do NOT touch it here.
__global__ __launch_bounds__(256) void gating_kernel(
    const float* __restrict__ ab, const float* __restrict__ dt_bias,
    const float* __restrict__ A_log, float* __restrict__ pk4)
{
    int i = blockIdx.x * 256 + threadIdx.x;
    int t = i >> 5, h = i & 31;
    float a  = ab[(size_t)t * 128 + h] + dt_bias[h];
    float sp = (a <= 20.f) ? log1pf(__expf(a)) : a;
    float gg = -__expf(A_log[h]) * sp;
    float b  = ab[(size_t)t * 128 + 32 + h];
    float eg = __expf(gg);
    float be = 1.f / (1.f + __expf(-b));
    pk4[(size_t)i * 4 + 0] = eg;
    pk4[(size_t)i * 4 + 1] = -be * eg;
    pk4[(size_t)i * 4 + 2] = be;
}

// ---------- gated delta-rule recurrence (v5) --------------------------------
// v5: second reduction moved OFF the S->S critical chain.
//   o_t = q.S_t = e^g*(q.S_{t-1}) + (q.k)*dvv   (q.k precomputed in conv_qk)
// Both dots (d1=k.S_old, d2=q.S_old) are computed concurrently and reduced by
// an interleaved dual DPP butterfly (red16x2): one chain of latency for two
// reductions. dvv = fma(-beta*e^g, d1, beta*v) — gate products precomputed.
// S*e^g runs concurrently with the reductions. Chain/step: dot partials ->
// 4 DPP adds -> dvv fma -> S pk_fma (~half of v3's chain; v3 had two serial
// red16 + rescale on-chain, which profiling identified as the ~310 stall
// cycles/step — VMEM was ruled out in round 3's null launch_bounds test).
__device__ __forceinline__ void gdn_step(
    f32x2 S[4], float4 kfa, float4 kfb, float4 qfa, float4 qfb,
    float egt, float nbt, float bvt, float qkt, bf16* optr, bool writer)
{
    f32x2 k2[4] = {{kfa.x, kfa.y}, {kfa.z, kfa.w}, {kfb.x, kfb.y}, {kfb.z, kfb.w}};
    f32x2 q2[4] = {{qfa.x, qfa.y}, {qfa.z, qfa.w}, {qfb.x, qfb.y}, {qfb.z, qfb.w}};
    // two independent dots off S_old
    f32x2 pd = pkfma(S[1], k2[1], S[0] * k2[0]);
    f32x2 pe = pkfma(S[3], k2[3], S[2] * k2[2]);
    f32x2 qd = pkfma(S[1], q2[1], S[0] * q2[0]);
    f32x2 qe = pkfma(S[3], q2[3], S[2] * q2[2]);
    // decay-scale of S: independent of the reductions, overlaps them
    f32x2 e2 = {egt, egt};
    f32x2 Se0 = S[0] * e2, Se1 = S[1] * e2, Se2 = S[2] * e2, Se3 = S[3] * e2;
    f32x2 ps = pd + pe;
    f32x2 qs = qd + qe;
    float d1 = ps.x + ps.y;
    float d2 = qs.x + qs.y;
    red16x2(d1, d2);
    float dvv = fmaf(nbt, d1, bvt);          // beta*(v - e^g*d1)
    f32x2 dv2 = {dvv, dvv};
    S[0] = pkfma(k2[0], dv2, Se0);
    S[1] = pkfma(k2[1], dv2, Se1);
    S[2] = pkfma(k2[2], dv2, Se2);
    S[3] = pkfma(k2[3], dv2, Se3);
    if (writer) *optr = __float2bfloat16(fmaf(qkt, dvv, egt * d2));
}

#define PF_DEPTH 8

__global__ __launch_bounds__(256, 1) void recur_kernel(
    const float* __restrict__ qn, const float* __restrict__ kn, const bf16* __restrict__ vv,
    const float* __restrict__ pk4, bf16* __restrict__ o)
{
    int h   = blockIdx.x;          // 0..31
    int sp  = blockIdx.y;          // 0..7
    int tid = threadIdx.x;
    int dvl = tid >> 4;            // 0..15
    int dkg = tid & 15;            // 0..15 : dk = dkg*8 .. +8
    int dv  = sp * 16 + dvl;
    int hkv = h >> 1;              // GQA repeat-interleave
    bool writer = (dkg == 0);

    const float* kp = kn + hkv * DKh + dkg * 8;
    const float* qp = qn + hkv * DKh + dkg * 8;
    const bf16*  vp = vv + h * DVh + dv;
    const float* gp = pk4 + h * 4;              // uniform addr -> scalar loads
    bf16* optr = o + h * DVh + dv;

    f32x2 S[4] = {{0.f, 0.f}, {0.f, 0.f}, {0.f, 0.f}, {0.f, 0.f}};

    // prefetch slots (rows t .. t+7). OOB reads (up to 8 rows past each array
    // end) land in the adjacent workspace allocation / pad; values unused.
    float4 ka[PF_DEPTH], kb[PF_DEPTH], qa[PF_DEPTH], qb[PF_DEPTH];
    float  es[PF_DEPTH], ns[PF_DEPTH], qs[PF_DEPTH], bv[PF_DEPTH];
    #pragma unroll
    for (int s = 0; s < PF_DEPTH; ++s) {
        ka[s] = *(const float4*)(kp + (size_t)s * 2048);
        kb[s] = *(const float4*)(kp + (size_t)s * 2048 + 4);
        qa[s] = *(const float4*)(qp + (size_t)s * 2048);
        qb[s] = *(const float4*)(qp + (size_t)s * 2048 + 4);
        float4 g4 = *(const float4*)(gp + (size_t)s * 128);
        float vcf = __bfloat162float(vp[(size_t)s * 4096]);
        es[s] = g4.x; ns[s] = g4.y; qs[s] = g4.w; bv[s] = g4.z * vcf;
    }
    const float* kl = kp + (size_t)PF_DEPTH * 2048;
    const float* ql = qp + (size_t)PF_DEPTH * 2048;
    const bf16*  vl = vp + (size_t)PF_DEPTH * 4096;
    const float* gl = gp + (size_t)PF_DEPTH * 128;

    #pragma unroll 1
    for (int t = 0; t < T_TOK; t += PF_DEPTH) {
        #pragma unroll
        for (int s = 0; s < PF_DEPTH; ++s) {
            float4 kfa = ka[s], kfb = kb[s], qfa = qa[s], qfb = qb[s];
            float egt = es[s], nbt = ns[s], qkt = qs[s], bvt = bv[s];
            // refill slot s with row t+s+PF_DEPTH (pad-covered when OOB)
            ka[s] = *(const float4*)(kl + (size_t)s * 2048);
            kb[s] = *(const float4*)(kl + (size_t)s * 2048 + 4);
            qa[s] = *(const float4*)(ql + (size_t)s * 2048);
            qb[s] = *(const float4*)(ql + (size_t)s * 2048 + 4);
            float4 g4 = *(const float4*)(gl + (size_t)s * 128);
            float vcf = __bfloat162float(vl[(size_t)s * 4096]);
            es[s] = g4.x; ns[s] = g4.y; qs[s] = g4.w; bv[s] = g4.z * vcf;
            gdn_step(S, kfa, kfb, qfa, qfb, egt, nbt, bvt, qkt,
                     optr + (size_t)(t + s) * 4096, writer);
        }
        kl += (size_t)PF_DEPTH * 2048;
        ql += (size_t)PF_DEPTH * 2048;
        vl += (size_t)PF_DEPTH * 4096;
        gl += (size_t)PF_DEPTH * 128;
    }
}

// ---------- gated RMSNorm ----------
__global__ __launch_bounds__(256) void normgate_kernel(
    const bf16* __restrict__ o, const bf16* __restrict__ gate,
    const float* __restrict__ w, bf16* __restrict__ og)
{
    int grp  = blockIdx.x * 4 + (threadIdx.x >> 6);
    int lane = threadIdx.x & 63;
    int t = grp >> 5, h = grp & 31;
    size_t base = (size_t)t * 4096 + h * DVh;
    uint32_t uo = *(const uint32_t*)(o + base + lane * 2);
    float a, b; bf2f(uo, a, b);
    float ss = a * a + b * b;
    #pragma unroll
    for (int m = 1; m < 64; m <<= 1) ss += __shfl_xor(ss, m, 64);
    float rn = rsqrtf(ss * (1.f / 128.f) + 1e-5f);
    uint32_t ug = *(const uint32_t*)(gate + base + lane * 2);
    float ga, gb; bf2f(ug, ga, gb);
    float wa = w[lane * 2], wb = w[lane * 2 + 1];
    float oa = a * rn * wa * (ga / (1.f + __expf(-ga)));
    float ob = b * rn * wb * (gb / (1.f + __expf(-gb)));
    og[base + lane * 2]     = __float2bfloat16(oa);
    og[base + lane * 2 + 1] = __float2bfloat16(ob);
}

// ---------- launch ----------
extern "C" void kernel_launch(void* const* d_in, const int* in_sizes, int n_in,
                              void* d_out, int out_size, void* d_ws, size_t ws_size,
                              hipStream_t stream)
{
    const float* h       = (const float*)d_in[0];
    const float* Wq      = (const float*)d_in[1];
    const float* Wk      = (const float*)d_in[2];
    const float* Wv      = (const float*)d_in[3];
    const float* Wa      = (const float*)d_in[4];
    const float* Wb      = (const float*)d_in[5];
    const float* Wg      = (const float*)d_in[6];
    const float* conv_q  = (const float*)d_in[7];
    const float* conv_k  = (const float*)d_in[8];
    const float* conv_v  = (const float*)d_in[9];
    const float* dt_bias = (const float*)d_in[10];
    const float* A_log   = (const float*)d_in[11];
    const float* onw     = (const float*)d_in[12];
    const float* Wo      = (const float*)d_in[13];
    float* out = (float*)d_out;

    char* ws = (char*)d_ws;
    bf16*  WqkvT = (bf16*)ws;   ws += (size_t)8192 * 2048 * 2;   // 33.5 MB
    bf16*  WgT   = (bf16*)ws;   ws += (size_t)4096 * 2048 * 2;   // 16.8 MB (reused as qnb)
    bf16*  WoT   = (bf16*)ws;   ws += (size_t)2048 * 4096 * 2;   // 16.8 MB
    bf16*  WabT  = (bf16*)ws;   ws += (size_t)128 * 2048 * 2;
    bf16*  hb    = (bf16*)ws;   ws += (size_t)2048 * 2048 * 2;
    bf16*  mixed = (bf16*)ws;   ws += (size_t)2048 * 8192 * 2;   // 33.5 MB
    float* ab    = (float*)ws;  ws += (size_t)2048 * 128 * 4;
    float* knb   = (float*)ws;  ws += (size_t)2048 * 2048 * 4;   // 16.8 MB fp32
    bf16*  vvb   = (bf16*)ws;   ws += (size_t)2048 * 4096 * 2;   // 16.8 MB
    float* pk4   = (float*)ws;  ws += (size_t)2048 * 32 * 4 * 4; // [t][h][{eg,-b*eg,b,qk}]
    ws += 32768;                                                 // OOB-prefetch pad
    // aliases over dead regions (stream-ordered lifetimes):
    float* qnb = (float*)WgT;                      // WgT dead after gate GEMM
    bf16*  ob   = WqkvT;                           // WqkvT dead after qkv GEMM
    bf16*  gate = WqkvT + (size_t)2048 * 4096;     // second half of WqkvT region
    bf16*  og   = mixed;                           // mixed dead after conv kernels

    dim3 tb(32, 8);
    transpose_kernel<<<dim3(64, 64),  tb, 0, stream>>>(Wq, WqkvT,                       2048, 2048);
    transpose_kernel<<<dim3(64, 64),  tb, 0, stream>>>(Wk, WqkvT + (size_t)2048 * 2048, 2048, 2048);
    transpose_kernel<<<dim3(128, 64), tb, 0, stream>>>(Wv, WqkvT + (size_t)4096 * 2048, 2048, 4096);
    transpose_kernel<<<dim3(128, 64), tb, 0, stream>>>(Wg, WgT,                         2048, 4096);
    transpose_kernel<<<dim3(64, 128), tb, 0, stream>>>(Wo, WoT,                         4096, 2048);
    build_wab_kernel<<<dim3(8, 128), 256, 0, stream>>>(Wa, Wb, WabT);
    f2b_kernel<<<16384, 256, 0, stream>>>(h, hb, 2048 * 2048);

    gemm_bt_kernel<bf16> <<<dim3(16, 64), 256, 0, stream>>>(hb, WqkvT, mixed, 2048, 8192, 2048);
    gemm_bt_kernel<float><<<dim3(16, 1),  256, 0, stream>>>(hb, WabT,  ab,    2048, 128,  2048);
    gemm_bt_kernel<bf16> <<<dim3(16, 32), 256, 0, stream>>>(hb, WgT,   gate,  2048, 4096, 2048);

    conv_qk_kernel<<<dim3(2048, 16), 128, 0, stream>>>(mixed, conv_q, conv_k, qnb, knb, pk4);
    conv_v_kernel<<<32768, 256, 0, stream>>>(mixed, conv_v, vvb);
    gating_kernel<<<256, 256, 0, stream>>>(ab, dt_bias, A_log, pk4);

    recur_kernel<<<dim3(32, 8), 256, 0, stream>>>(qnb, knb, vvb, pk4, ob);
    normgate_kernel<<<16384, 256, 0, stream>>>(ob, gate, onw, og);

    gemm_bt_kernel<float><<<dim3(16, 16), 256, 0, stream>>>(og, WoT, out, 2048, 2048, 4096);
}